// Round 1
// baseline (192.228 us; speedup 1.0000x reference)
//
#include <hip/hip_runtime.h>
#include <math.h>

#define BB 64
#define NN 512
#define FF 128

// ---------------- Kernel 1: row softmax of weight [N,N] -> S ----------------
__global__ __launch_bounds__(256) void softmax_kernel(const float* __restrict__ w,
                                                      float* __restrict__ S) {
    const int row = blockIdx.x;
    const float* wr = w + (size_t)row * NN;
    float* sr = S + (size_t)row * NN;
    const int tid = threadIdx.x;
    const int wave = tid >> 6, lane = tid & 63;

    float v0 = wr[tid];
    float v1 = wr[tid + 256];

    // --- max reduce ---
    float m = fmaxf(v0, v1);
    #pragma unroll
    for (int off = 32; off > 0; off >>= 1)
        m = fmaxf(m, __shfl_down(m, off, 64));
    __shared__ float red[8];
    if (lane == 0) red[wave] = m;
    __syncthreads();
    if (tid == 0) {
        float mm = fmaxf(fmaxf(red[0], red[1]), fmaxf(red[2], red[3]));
        red[4] = mm;
    }
    __syncthreads();
    m = red[4];

    float e0 = expf(v0 - m);
    float e1 = expf(v1 - m);

    // --- sum reduce ---
    float s = e0 + e1;
    #pragma unroll
    for (int off = 32; off > 0; off >>= 1)
        s += __shfl_down(s, off, 64);
    __syncthreads();               // red[0..3] reuse hygiene
    if (lane == 0) red[wave] = s;
    __syncthreads();
    if (tid == 0) red[5] = 1.0f / (red[0] + red[1] + red[2] + red[3]);
    __syncthreads();
    const float inv = red[5];

    sr[tid]       = e0 * inv;
    sr[tid + 256] = e1 * inv;
}

// ------------- Kernel 2: d[b,i] = rsqrt(1 + sum_j S[i,j]*mask[b,i,j]) -------
__global__ __launch_bounds__(256) void rowsum_kernel(const float* __restrict__ S,
                                                     const float* __restrict__ mask,
                                                     float* __restrict__ dvec) {
    const int gwave = (int)((blockIdx.x * 256u + threadIdx.x) >> 6); // global wave id = b*N+i
    const int lane = threadIdx.x & 63;
    const int b = gwave >> 9;      // / N
    const int i = gwave & (NN - 1);

    const float4* mrow = (const float4*)(mask + ((size_t)b * NN + i) * NN);
    const float4* srow = (const float4*)(S + (size_t)i * NN);

    float sum = 0.f;
    #pragma unroll
    for (int k = 0; k < 2; k++) {
        int idx = lane + k * 64;   // 128 float4 per row
        float4 mv = mrow[idx];
        float4 sv = srow[idx];
        sum += mv.x * sv.x + mv.y * sv.y + mv.z * sv.z + mv.w * sv.w;
    }
    #pragma unroll
    for (int off = 32; off > 0; off >>= 1)
        sum += __shfl_down(sum, off, 64);
    if (lane == 0) {
        float rs = sum + 1.0f;     // identity diagonal
        dvec[gwave] = (rs > 0.f) ? (1.0f / sqrtf(rs)) : 0.f;
    }
}

// ------------- Kernel 3: out[b] = D (A_masked D X + D X_diag) ---------------
// block: one batch b, 32-row i-tile; 256 threads = 32 f4-lanes x 8 i-slots,
// 4 rows per thread (stride 8).
#define TI 32
#define TJ 64
__global__ __launch_bounds__(256) void matmul_kernel(const float* __restrict__ S,
                                                     const float* __restrict__ mask,
                                                     const float* __restrict__ dvec,
                                                     const float* __restrict__ in,
                                                     float* __restrict__ out) {
    __shared__ float aT[TI][TJ];

    const int b = blockIdx.y;
    const int i_base = blockIdx.x * TI;
    const int tid = threadIdx.x;
    const int f_id = tid & 31;   // float4 column index (F/4 = 32)
    const int i_id = tid >> 5;   // 0..7

    const float4* in4 = (const float4*)(in + (size_t)b * NN * FF);
    const float* dB = dvec + b * NN;

    float4 acc[4];
    #pragma unroll
    for (int r = 0; r < 4; r++) acc[r] = make_float4(0.f, 0.f, 0.f, 0.f);

    for (int j0 = 0; j0 < NN; j0 += TJ) {
        __syncthreads();  // protect aT reads of previous chunk
        // stage a[i][j] = S[i,j] * mask[b,i,j] * d[b,j]  (32x64 = 2048 vals, 8/thread)
        #pragma unroll
        for (int k = 0; k < 8; k++) {
            int idx = tid + k * 256;
            int il = idx >> 6;
            int jl = idx & 63;
            int gi = i_base + il;
            int gj = j0 + jl;
            float a = S[(size_t)gi * NN + gj] * mask[((size_t)b * NN + gi) * NN + gj] * dB[gj];
            aT[il][jl] = a;
        }
        __syncthreads();

        #pragma unroll 4
        for (int j = 0; j < TJ; j++) {
            float4 x = in4[(size_t)(j0 + j) * (FF / 4) + f_id];
            #pragma unroll
            for (int r = 0; r < 4; r++) {
                float a = aT[i_id + 8 * r][j];
                acc[r].x += a * x.x;
                acc[r].y += a * x.y;
                acc[r].z += a * x.z;
                acc[r].w += a * x.w;
            }
        }
    }

    // epilogue: out = d_i * (acc + d_i * x_i)
    float4* out4 = (float4*)(out + (size_t)b * NN * FF);
    #pragma unroll
    for (int r = 0; r < 4; r++) {
        int i = i_base + i_id + 8 * r;
        float di = dB[i];
        float4 x = in4[(size_t)i * (FF / 4) + f_id];
        float4 o;
        o.x = di * (acc[r].x + di * x.x);
        o.y = di * (acc[r].y + di * x.y);
        o.z = di * (acc[r].z + di * x.z);
        o.w = di * (acc[r].w + di * x.w);
        out4[(size_t)i * (FF / 4) + f_id] = o;
    }
}

extern "C" void kernel_launch(void* const* d_in, const int* in_sizes, int n_in,
                              void* d_out, int out_size, void* d_ws, size_t ws_size,
                              hipStream_t stream) {
    const float* inp  = (const float*)d_in[0];   // [B,N,F]
    const float* mask = (const float*)d_in[1];   // [B,N,N]
    const float* w    = (const float*)d_in[2];   // [N,N]
    float* out = (float*)d_out;                  // [B,N,F]

    float* S    = (float*)d_ws;                  // N*N floats
    float* dvec = S + (size_t)NN * NN;           // B*N floats

    softmax_kernel<<<NN, 256, 0, stream>>>(w, S);
    rowsum_kernel<<<(BB * NN) / 4, 256, 0, stream>>>(S, mask, dvec);
    dim3 g3(NN / TI, BB);
    matmul_kernel<<<g3, 256, 0, stream>>>(S, mask, dvec, inp, out);
}

// Round 2
// 151.514 us; speedup vs baseline: 1.2687x; 1.2687x over previous
//
#include <hip/hip_runtime.h>
#include <math.h>

#define BB 64
#define NN 512
#define FF 128

typedef __bf16 bf16x8 __attribute__((ext_vector_type(8)));
typedef float floatx4 __attribute__((ext_vector_type(4)));

// round-to-nearest-even f32 -> bf16 bits (bit-trick, no __bf16 cast needed)
__device__ __forceinline__ unsigned int bf16u(float f) {
    unsigned int u = __builtin_bit_cast(unsigned int, f);
    unsigned int r = (u + 0x7FFFu + ((u >> 16) & 1u)) >> 16;
    return r & 0xFFFFu;
}

// ---------------- Kernel 1: row softmax of weight [N,N] -> S ----------------
__global__ __launch_bounds__(256) void softmax_kernel(const float* __restrict__ w,
                                                      float* __restrict__ S) {
    const int row = blockIdx.x;
    const float* wr = w + (size_t)row * NN;
    float* sr = S + (size_t)row * NN;
    const int tid = threadIdx.x;
    const int wave = tid >> 6, lane = tid & 63;

    float v0 = wr[tid];
    float v1 = wr[tid + 256];

    float m = fmaxf(v0, v1);
    #pragma unroll
    for (int off = 32; off > 0; off >>= 1)
        m = fmaxf(m, __shfl_down(m, off, 64));
    __shared__ float red[8];
    if (lane == 0) red[wave] = m;
    __syncthreads();
    if (tid == 0) red[4] = fmaxf(fmaxf(red[0], red[1]), fmaxf(red[2], red[3]));
    __syncthreads();
    m = red[4];

    float e0 = expf(v0 - m);
    float e1 = expf(v1 - m);

    float s = e0 + e1;
    #pragma unroll
    for (int off = 32; off > 0; off >>= 1)
        s += __shfl_down(s, off, 64);
    __syncthreads();
    if (lane == 0) red[wave] = s;
    __syncthreads();
    if (tid == 0) red[5] = 1.0f / (red[0] + red[1] + red[2] + red[3]);
    __syncthreads();
    const float inv = red[5];

    sr[tid]       = e0 * inv;
    sr[tid + 256] = e1 * inv;
}

// ------------- Kernel 2: d[b,i] = rsqrt(1 + sum_j S[i,j]*mask[b,i,j]) -------
__global__ __launch_bounds__(256) void rowsum_kernel(const float* __restrict__ S,
                                                     const float* __restrict__ mask,
                                                     float* __restrict__ dvec) {
    const int gwave = (int)((blockIdx.x * 256u + threadIdx.x) >> 6); // = b*N+i
    const int lane = threadIdx.x & 63;
    const int b = gwave >> 9;
    const int i = gwave & (NN - 1);

    const float4* mrow = (const float4*)(mask + ((size_t)b * NN + i) * NN);
    const float4* srow = (const float4*)(S + (size_t)i * NN);

    float sum = 0.f;
    #pragma unroll
    for (int k = 0; k < 2; k++) {
        int idx = lane + k * 64;
        float4 mv = mrow[idx];
        float4 sv = srow[idx];
        sum += mv.x * sv.x + mv.y * sv.y + mv.z * sv.z + mv.w * sv.w;
    }
    #pragma unroll
    for (int off = 32; off > 0; off >>= 1)
        sum += __shfl_down(sum, off, 64);
    if (lane == 0) {
        float rs = sum + 1.0f;
        dvec[gwave] = (rs > 0.f) ? (1.0f / sqrtf(rs)) : 0.f;
    }
}

// ------------- Kernel 3: MFMA matmul  out[b] = D (S∘M) D X + D^2 X ----------
// block: (b, 32-row i-tile), 256 thr = 4 waves.
// wave w: rows iw=(w&1)*16 .. +16, cols fw=(w>>1)*64 .. +64 (4 n-tiles of 16).
// K-chunk = 64 (2 MFMA K-steps of 32).
#define TI 32
#define TK 64
#define ASTR 72   // LDS row stride in bf16 elems (144 B: 16B-aligned, ~2-way banks)

__global__ __launch_bounds__(256) void matmul_kernel(const float* __restrict__ S,
                                                     const float* __restrict__ mask,
                                                     const float* __restrict__ dvec,
                                                     const float* __restrict__ in,
                                                     float* __restrict__ out) {
    __shared__ unsigned short Alds[TI * ASTR];   //  A = S*mask (bf16), [i][j]
    __shared__ unsigned short Xlds[FF * ASTR];   //  Xt = d_j*x   (bf16), [f][j]

    const int b = blockIdx.y;
    const int i_base = blockIdx.x * TI;
    const int tid = threadIdx.x;
    const int w = tid >> 6;
    const int lane = tid & 63;
    const int quad = lane >> 4;
    const int l16 = lane & 15;
    const int iw = (w & 1) * 16;
    const int fw = (w >> 1) * 64;

    const float* dB = dvec + b * NN;

    floatx4 acc[4];
    #pragma unroll
    for (int nt = 0; nt < 4; nt++) acc[nt] = (floatx4){0.f, 0.f, 0.f, 0.f};

    // staging thread mappings (fixed per thread)
    const int a_il = tid >> 3;          // 0..31 row
    const int a_js = (tid & 7) * 8;     // j offset 0..56
    const int x_jl = tid & 63;          // j lane for X transpose (conflict-free)
    const int x_f0 = (tid >> 6) * 32;   // f segment

    for (int j0 = 0; j0 < NN; j0 += TK) {
        __syncthreads();   // previous chunk's frag reads done before overwrite

        // ---- stage A[i][j] = S[i,j]*mask[b,i,j] -> bf16 (8 elems/thread) ----
        {
            const float4* mrow = (const float4*)(mask + ((size_t)b * NN + i_base + a_il) * NN + j0 + a_js);
            const float4* srow = (const float4*)(S + (size_t)(i_base + a_il) * NN + j0 + a_js);
            float4 m0 = mrow[0], m1 = mrow[1];
            float4 s0 = srow[0], s1 = srow[1];
            uint4 pk;
            pk.x = bf16u(m0.x * s0.x) | (bf16u(m0.y * s0.y) << 16);
            pk.y = bf16u(m0.z * s0.z) | (bf16u(m0.w * s0.w) << 16);
            pk.z = bf16u(m1.x * s1.x) | (bf16u(m1.y * s1.y) << 16);
            pk.w = bf16u(m1.z * s1.z) | (bf16u(m1.w * s1.w) << 16);
            *((uint4*)&Alds[a_il * ASTR + a_js]) = pk;
        }

        // ---- stage Xt[f][j] = bf16(d_j * x[b][j][f])  (32 elems/thread) ----
        {
            float dj = dB[j0 + x_jl];
            const float4* xp = (const float4*)(in + ((size_t)b * NN + j0 + x_jl) * FF + x_f0);
            #pragma unroll
            for (int c = 0; c < 8; c++) {
                float4 xv = xp[c];
                int fb = x_f0 + 4 * c;
                Xlds[(fb + 0) * ASTR + x_jl] = (unsigned short)bf16u(xv.x * dj);
                Xlds[(fb + 1) * ASTR + x_jl] = (unsigned short)bf16u(xv.y * dj);
                Xlds[(fb + 2) * ASTR + x_jl] = (unsigned short)bf16u(xv.z * dj);
                Xlds[(fb + 3) * ASTR + x_jl] = (unsigned short)bf16u(xv.w * dj);
            }
        }

        __syncthreads();

        // ---- MFMA: 2 K-steps x 4 n-tiles ----
        #pragma unroll
        for (int s = 0; s < 2; s++) {
            // A-frag: lane holds A[m=iw+l16][k = s*32 + quad*8 + 0..7]
            bf16x8 af = *(const bf16x8*)&Alds[(iw + l16) * ASTR + s * 32 + quad * 8];
            #pragma unroll
            for (int nt = 0; nt < 4; nt++) {
                // B-frag: lane holds B[n=fw+nt*16+l16][k = s*32 + quad*8 + 0..7]
                bf16x8 bfr = *(const bf16x8*)&Xlds[(fw + nt * 16 + l16) * ASTR + s * 32 + quad * 8];
                acc[nt] = __builtin_amdgcn_mfma_f32_16x16x32_bf16(af, bfr, acc[nt], 0, 0, 0);
            }
        }
    }

    // ---- epilogue: out = d_i * (acc + d_i * x_i), fp32 exact identity term --
    #pragma unroll
    for (int nt = 0; nt < 4; nt++) {
        int f = fw + nt * 16 + l16;
        #pragma unroll
        for (int r = 0; r < 4; r++) {
            int i = i_base + iw + quad * 4 + r;
            float di = dB[i];
            float x = in[((size_t)b * NN + i) * FF + f];
            out[((size_t)b * NN + i) * FF + f] = di * (acc[nt][r] + di * x);
        }
    }
}

extern "C" void kernel_launch(void* const* d_in, const int* in_sizes, int n_in,
                              void* d_out, int out_size, void* d_ws, size_t ws_size,
                              hipStream_t stream) {
    const float* inp  = (const float*)d_in[0];   // [B,N,F]
    const float* mask = (const float*)d_in[1];   // [B,N,N]
    const float* w    = (const float*)d_in[2];   // [N,N]
    float* out = (float*)d_out;                  // [B,N,F]

    float* S    = (float*)d_ws;                  // N*N floats
    float* dvec = S + (size_t)NN * NN;           // B*N floats

    softmax_kernel<<<NN, 256, 0, stream>>>(w, S);
    rowsum_kernel<<<(BB * NN) / 4, 256, 0, stream>>>(S, mask, dvec);
    dim3 g3(NN / TI, BB);
    matmul_kernel<<<g3, 256, 0, stream>>>(S, mask, dvec, inp, out);
}